// Round 3
// baseline (586.756 us; speedup 1.0000x reference)
//
#include <hip/hip_runtime.h>
#include <math.h>

#define NN 50000
#define EE 800000
#define JTOT 384   // 256 feat + 128 mz (bf16 rows of yb)

typedef short s8v __attribute__((ext_vector_type(8)));
typedef float f4v __attribute__((ext_vector_type(4)));

__device__ inline unsigned short f2bf(float f) {
    unsigned u = __float_as_uint(f);
    unsigned r = (u + 0x7FFFu + ((u >> 16) & 1u)) >> 16;   // RTNE
    return (unsigned short)r;
}
__device__ inline float bf2f(unsigned short u) {
    return __uint_as_float((unsigned)u << 16);
}

// ---------------- prep: zero degree counts + transpose merger_w ----------------
__global__ void prep_kernel(int* counts, const float* merger_w, float* mwT) {
    int i = blockIdx.x * blockDim.x + threadIdx.x;
    if (i < NN) counts[i] = 0;
    if (i < 192 * 64) {
        int r = i >> 6, c = i & 63;
        mwT[i] = merger_w[c * 192 + r];
    }
}

// ---------------- bf16 conversion: x -> xb, [fc_w;gate_m_w] -> wb ----------------
__global__ void cvt_kernel(const float* __restrict__ x, const float* __restrict__ fc_w,
                           const float* __restrict__ gate_m_w,
                           unsigned short* __restrict__ xb, unsigned short* __restrict__ wb) {
    int stride = gridDim.x * blockDim.x;
    int tid = blockIdx.x * blockDim.x + threadIdx.x;
    const int total_x4 = NN * 128 / 4;
    for (int i = tid; i < total_x4; i += stride) {
        float4 v = ((const float4*)x)[i];
        ushort4 o;
        o.x = f2bf(v.x); o.y = f2bf(v.y); o.z = f2bf(v.z); o.w = f2bf(v.w);
        ((ushort4*)xb)[i] = o;
    }
    for (int i = tid; i < 384 * 128; i += stride)
        wb[i] = f2bf(i < 256 * 128 ? fc_w[i] : gate_m_w[i - 256 * 128]);
}

// ---------------- CSR build ----------------
__global__ void count_kernel(const int* __restrict__ dst, int* counts) {
    for (int i = blockIdx.x * blockDim.x + threadIdx.x; i < EE; i += gridDim.x * blockDim.x)
        atomicAdd(&counts[dst[i]], 1);
}

__global__ __launch_bounds__(1024) void scan_kernel(const int* __restrict__ counts,
                                                    int* row_start, int* cursor) {
    __shared__ int sm[1024];
    const int per = (NN + 1023) / 1024;
    int t = threadIdx.x;
    int base = t * per;
    int s = 0;
    for (int i = 0; i < per; ++i) {
        int idx = base + i;
        if (idx < NN) s += counts[idx];
    }
    sm[t] = s;
    __syncthreads();
    for (int off = 1; off < 1024; off <<= 1) {
        int v = (t >= off) ? sm[t - off] : 0;
        __syncthreads();
        sm[t] += v;
        __syncthreads();
    }
    int run = sm[t] - s;
    for (int i = 0; i < per; ++i) {
        int idx = base + i;
        if (idx < NN) {
            row_start[idx] = run;
            cursor[idx] = run;
            run += counts[idx];
        }
    }
    if (t == 1023) row_start[NN] = sm[1023];
}

__global__ void scatter_kernel(const int* __restrict__ src, const int* __restrict__ dst,
                               const float* __restrict__ weight, int* cursor,
                               int* src_sorted, float* w_sorted) {
    for (int i = blockIdx.x * blockDim.x + threadIdx.x; i < EE; i += gridDim.x * blockDim.x) {
        int pos = atomicAdd(&cursor[dst[i]], 1);
        src_sorted[pos] = src[i];
        w_sorted[pos] = weight[i];
    }
}

// ---------------- MFMA GEMM -> yb (bf16), fused el/er epilogue ----------------
// 128x128 tile, K=128 staged. 4 waves 2x2; each wave 64x64 out = 4x4 frags.
__global__ __launch_bounds__(256) void gemm_mfma(const unsigned short* __restrict__ xb,
                                                 const unsigned short* __restrict__ wb,
                                                 const float* __restrict__ gate_m_b,
                                                 const float* __restrict__ attn_l,
                                                 const float* __restrict__ attn_r,
                                                 unsigned short* __restrict__ yb,
                                                 float* __restrict__ el,
                                                 float* __restrict__ er) {
    __shared__ unsigned short lx[128 * 136];
    __shared__ unsigned short lw[128 * 136];
    int tid = threadIdx.x;
    int row0 = blockIdx.x * 128;
    int jc = blockIdx.y;   // 0,1: feat halves (heads 2jc,2jc+1); 2: mz

    #pragma unroll
    for (int c = 0; c < 8; ++c) {
        int chunk = c * 256 + tid;
        int r = chunk >> 4, seg = chunk & 15;
        int gr = row0 + r; if (gr >= NN) gr = NN - 1;
        *(s8v*)&lx[r * 136 + seg * 8] = *(const s8v*)&xb[(size_t)gr * 128 + seg * 8];
        *(s8v*)&lw[r * 136 + seg * 8] = *(const s8v*)&wb[(size_t)(jc * 128 + r) * 128 + seg * 8];
    }
    __syncthreads();

    int lane = tid & 63, w = tid >> 6;
    int wr = w >> 1, wc = w & 1;
    int lrow = lane & 15, lhi = lane >> 4;
    f4v acc[4][4] = {};
    const unsigned short* pax = &lx[(wr * 64 + lrow) * 136 + lhi * 8];
    const unsigned short* pbw = &lw[(wc * 64 + lrow) * 136 + lhi * 8];
    #pragma unroll
    for (int kk = 0; kk < 4; ++kk) {
        s8v a[4], b[4];
        #pragma unroll
        for (int mi = 0; mi < 4; ++mi) a[mi] = *(const s8v*)(pax + mi * 16 * 136 + kk * 32);
        #pragma unroll
        for (int ni = 0; ni < 4; ++ni) b[ni] = *(const s8v*)(pbw + ni * 16 * 136 + kk * 32);
        #pragma unroll
        for (int mi = 0; mi < 4; ++mi)
            #pragma unroll
            for (int ni = 0; ni < 4; ++ni)
                acc[mi][ni] = __builtin_amdgcn_mfma_f32_16x16x32_bf16(a[mi], b[ni], acc[mi][ni], 0, 0, 0);
    }

    // store bf16 (+bias on mz cols)
    #pragma unroll
    for (int ni = 0; ni < 4; ++ni) {
        int gcol = jc * 128 + wc * 64 + ni * 16 + lrow;
        float bias = (gcol >= 256) ? gate_m_b[gcol - 256] : 0.0f;
        #pragma unroll
        for (int mi = 0; mi < 4; ++mi) {
            int grow0 = row0 + wr * 64 + mi * 16 + lhi * 4;
            #pragma unroll
            for (int rg = 0; rg < 4; ++rg) {
                int grow = grow0 + rg;
                if (grow < NN) yb[(size_t)grow * JTOT + gcol] = f2bf(acc[mi][ni][rg] + bias);
            }
        }
    }

    // fused el/er: this wave covers head = jc*2+wc fully (64 cols)
    if (jc < 2) {
        int head = jc * 2 + wc;
        #pragma unroll
        for (int mi = 0; mi < 4; ++mi) {
            float tl[4] = {0, 0, 0, 0}, tr[4] = {0, 0, 0, 0};
            #pragma unroll
            for (int ni = 0; ni < 4; ++ni) {
                float al = attn_l[head * 64 + ni * 16 + lrow];
                float ar = attn_r[head * 64 + ni * 16 + lrow];
                #pragma unroll
                for (int rg = 0; rg < 4; ++rg) {
                    tl[rg] += acc[mi][ni][rg] * al;
                    tr[rg] += acc[mi][ni][rg] * ar;
                }
            }
            #pragma unroll
            for (int off = 1; off < 16; off <<= 1) {
                #pragma unroll
                for (int rg = 0; rg < 4; ++rg) {
                    tl[rg] += __shfl_xor(tl[rg], off, 64);
                    tr[rg] += __shfl_xor(tr[rg], off, 64);
                }
            }
            if (lrow == 0) {
                int grow0 = row0 + wr * 64 + mi * 16 + lhi * 4;
                #pragma unroll
                for (int rg = 0; rg < 4; ++rg) {
                    int grow = grow0 + rg;
                    if (grow < NN) {
                        el[grow * 4 + head] = tl[rg];
                        er[grow * 4 + head] = tr[rg];
                    }
                }
            }
        }
    }
}

// ---------------- single-pass per-node aggregation + gate + merger ----------------
// lane owns head h=lane>>4, cols 4*(lane&15)..+3 of that head.
__global__ __launch_bounds__(256) void node_kernel(const float* __restrict__ x,
                                                   const unsigned short* __restrict__ yb,
                                                   const unsigned short* __restrict__ xb,
                                                   const float* __restrict__ el,
                                                   const float* __restrict__ er,
                                                   const int* __restrict__ row_start,
                                                   const int* __restrict__ src_sorted,
                                                   const float* __restrict__ w_sorted,
                                                   const float* __restrict__ gate_fn_w,
                                                   const float* __restrict__ gate_fn_b,
                                                   const float* __restrict__ mwT,
                                                   const float* __restrict__ merger_b,
                                                   float* __restrict__ out) {
    int lane = threadIdx.x & 63, wv = threadIdx.x >> 6;
    int n = blockIdx.x * 4 + wv;
    if (n >= NN) return;
    int rs = row_start[n], re = row_start[n + 1];
    bool s1 = (lane & 16) != 0, s2 = (lane & 32) != 0;

    float4 er4 = ((const float4*)er)[n];
    float e01 = s1 ? er4.y : er4.x;
    float e23 = s1 ? er4.w : er4.z;
    float ern = s2 ? e23 : e01;

    float2 x2 = *(const float2*)(x + (size_t)n * 128 + 2 * lane);

    float mz0 = -INFINITY, mz1 = -INFINITY;
    float sx0 = 0.f, sx1 = 0.f, se = 0.f;
    float ac0 = 0.f, ac1 = 0.f, ac2 = 0.f, ac3 = 0.f;

    for (int idx = rs; idx < re; ++idx) {
        int s = src_sorted[idx];
        float wgt = w_sorted[idx];
        float4 el4 = ((const float4*)el)[s];
        const unsigned short* yr = yb + (size_t)s * JTOT;
        ushort4 f4 = *(const ushort4*)(yr + 4 * lane);            // feat[h*64 + 4cg ..]
        ushort2 m2 = *(const ushort2*)(yr + 256 + 2 * lane);      // mz[2l..2l+1]
        ushort2 xg = *(const ushort2*)(xb + (size_t)s * 128 + 2 * lane);

        float l01 = s1 ? el4.y : el4.x;
        float l23 = s1 ? el4.w : el4.z;
        float t = (s2 ? l23 : l01) + ern;
        t = (t > 0.f) ? t : 0.2f * t;
        float ex = __expf(t);
        se += ex;
        float axw = ex * wgt;
        ac0 += axw * bf2f(f4.x);
        ac1 += axw * bf2f(f4.y);
        ac2 += axw * bf2f(f4.z);
        ac3 += axw * bf2f(f4.w);
        mz0 = fmaxf(mz0, bf2f(m2.x));
        mz1 = fmaxf(mz1, bf2f(m2.y));
        sx0 += bf2f(xg.x);
        sx1 += bf2f(xg.y);
    }
    if (re == rs) { mz0 = mz1 = 0.f; }   // unreachable (self-loops) but safe
    float deg = (float)(re - rs);
    float invd = 1.0f / fmaxf(deg, 1.0f);
    float mn0 = sx0 * invd, mn1 = sx1 * invd;

    float gate[4];
    #pragma unroll
    for (int h = 0; h < 4; ++h) {
        const float* gw = gate_fn_w + h * 384;
        float2 g0 = *(const float2*)(gw + 2 * lane);
        float2 g1 = *(const float2*)(gw + 128 + 2 * lane);
        float2 g2 = *(const float2*)(gw + 256 + 2 * lane);
        float p = g0.x * x2.x + g0.y * x2.y + g1.x * mz0 + g1.y * mz1
                + g2.x * mn0 + g2.y * mn1;
        #pragma unroll
        for (int o = 1; o < 64; o <<= 1) p += __shfl_xor(p, o, 64);
        gate[h] = 1.0f / (1.0f + __expf(-(p + gate_fn_b[h])));
    }
    float g01 = s1 ? gate[1] : gate[0];
    float g23 = s1 ? gate[3] : gate[2];
    float gown = s2 ? g23 : g01;
    float scale = gown / fmaxf(se, 1e-30f);

    float p0 = ac0 * scale, p1 = ac1 * scale, p2 = ac2 * scale, p3 = ac3 * scale;
    p0 += __shfl_xor(p0, 16, 64); p1 += __shfl_xor(p1, 16, 64);
    p2 += __shfl_xor(p2, 16, 64); p3 += __shfl_xor(p3, 16, 64);
    p0 += __shfl_xor(p0, 32, 64); p1 += __shfl_xor(p1, 32, 64);
    p2 += __shfl_xor(p2, 32, 64); p3 += __shfl_xor(p3, 32, 64);
    p0 *= 0.25f; p1 *= 0.25f; p2 *= 0.25f; p3 *= 0.25f;
    // lane now holds gated[4*(lane&15) .. +3], replicated across head groups

    float val = merger_b[lane];
    #pragma unroll
    for (int i = 0; i < 128; ++i) {
        float xv = __shfl((i & 1) ? x2.y : x2.x, i >> 1, 64);
        val += xv * mwT[i * 64 + lane];
    }
    #pragma unroll
    for (int i = 0; i < 64; ++i) {
        float comp = ((i & 3) == 0) ? p0 : ((i & 3) == 1) ? p1 : ((i & 3) == 2) ? p2 : p3;
        float gv = __shfl(comp, i >> 2, 64);
        val += gv * mwT[(128 + i) * 64 + lane];
    }
    out[(size_t)n * 64 + lane] = val;
}

extern "C" void kernel_launch(void* const* d_in, const int* in_sizes, int n_in,
                              void* d_out, int out_size, void* d_ws, size_t ws_size,
                              hipStream_t stream) {
    const float* x         = (const float*)d_in[0];
    const int*   src       = (const int*)d_in[1];
    const int*   dst       = (const int*)d_in[2];
    const float* weight    = (const float*)d_in[3];
    const float* fc_w      = (const float*)d_in[4];
    const float* attn_l    = (const float*)d_in[5];
    const float* attn_r    = (const float*)d_in[6];
    const float* gate_m_w  = (const float*)d_in[7];
    const float* gate_m_b  = (const float*)d_in[8];
    const float* gate_fn_w = (const float*)d_in[9];
    const float* gate_fn_b = (const float*)d_in[10];
    const float* merger_w  = (const float*)d_in[11];
    const float* merger_b  = (const float*)d_in[12];
    float* out = (float*)d_out;

    char* p = (char*)d_ws;
    auto alloc = [&](size_t bytes) {
        char* r = p;
        p += (bytes + 255) & ~(size_t)255;
        return r;
    };
    unsigned short* yb = (unsigned short*)alloc((size_t)NN * JTOT * 2);
    float* el          = (float*)alloc((size_t)NN * 4 * 4);
    float* er          = (float*)alloc((size_t)NN * 4 * 4);
    int*   counts      = (int*)alloc((size_t)NN * 4);
    int*   row_start   = (int*)alloc((size_t)(NN + 1) * 4);
    int*   cursor      = (int*)alloc((size_t)NN * 4);
    int*   src_sorted  = (int*)alloc((size_t)EE * 4);
    float* w_sorted    = (float*)alloc((size_t)EE * 4);
    float* mwT         = (float*)alloc((size_t)192 * 64 * 4);
    unsigned short* xb = (unsigned short*)alloc((size_t)NN * 128 * 2);
    unsigned short* wb = (unsigned short*)alloc((size_t)384 * 128 * 2);

    prep_kernel<<<(NN + 255) / 256, 256, 0, stream>>>(counts, merger_w, mwT);
    cvt_kernel<<<1024, 256, 0, stream>>>(x, fc_w, gate_m_w, xb, wb);
    count_kernel<<<1024, 256, 0, stream>>>(dst, counts);
    scan_kernel<<<1, 1024, 0, stream>>>(counts, row_start, cursor);
    scatter_kernel<<<1024, 256, 0, stream>>>(src, dst, weight, cursor, src_sorted, w_sorted);
    gemm_mfma<<<dim3((NN + 127) / 128, 3), 256, 0, stream>>>(xb, wb, gate_m_b, attn_l, attn_r,
                                                             yb, el, er);
    node_kernel<<<NN / 4, 256, 0, stream>>>(x, yb, xb, el, er, row_start, src_sorted, w_sorted,
                                            gate_fn_w, gate_fn_b, mwT, merger_b, out);
}

// Round 4
// 416.612 us; speedup vs baseline: 1.4084x; 1.4084x over previous
//
#include <hip/hip_runtime.h>
#include <math.h>

#define NN 50000
#define EE 800000
#define JTOT 384   // 256 feat + 128 mz (bf16 rows of yb)

typedef short s8v __attribute__((ext_vector_type(8)));
typedef float f4v __attribute__((ext_vector_type(4)));

__device__ inline unsigned short f2bf(float f) {
    unsigned u = __float_as_uint(f);
    unsigned r = (u + 0x7FFFu + ((u >> 16) & 1u)) >> 16;   // RTNE
    return (unsigned short)r;
}
__device__ inline float bf2f(unsigned short u) {
    return __uint_as_float((unsigned)u << 16);
}

// ---------------- cvt + zero counts: x->xb, [fc_w;gate_m_w]->wb, merger_w->wmb ----------------
__global__ void cvt_kernel(const float* __restrict__ x, const float* __restrict__ fc_w,
                           const float* __restrict__ gate_m_w, const float* __restrict__ merger_w,
                           unsigned short* __restrict__ xb, unsigned short* __restrict__ wb,
                           unsigned short* __restrict__ wmb, int* counts) {
    int stride = gridDim.x * blockDim.x;
    int tid = blockIdx.x * blockDim.x + threadIdx.x;
    const int total_x4 = NN * 128 / 4;
    for (int i = tid; i < total_x4; i += stride) {
        float4 v = ((const float4*)x)[i];
        ushort4 o;
        o.x = f2bf(v.x); o.y = f2bf(v.y); o.z = f2bf(v.z); o.w = f2bf(v.w);
        ((ushort4*)xb)[i] = o;
    }
    for (int i = tid; i < 384 * 128; i += stride)
        wb[i] = f2bf(i < 256 * 128 ? fc_w[i] : gate_m_w[i - 256 * 128]);
    for (int i = tid; i < 64 * 192; i += stride)
        wmb[i] = f2bf(merger_w[i]);
    for (int i = tid; i < NN; i += stride)
        counts[i] = 0;
}

// ---------------- CSR build ----------------
__global__ void count_kernel(const int* __restrict__ dst, int* counts) {
    for (int i = blockIdx.x * blockDim.x + threadIdx.x; i < EE; i += gridDim.x * blockDim.x)
        atomicAdd(&counts[dst[i]], 1);
}

__global__ __launch_bounds__(1024) void scan_kernel(const int* __restrict__ counts,
                                                    int* row_start, int* cursor) {
    __shared__ int sm[1024];
    const int per = (NN + 1023) / 1024;
    int t = threadIdx.x;
    int base = t * per;
    int s = 0;
    for (int i = 0; i < per; ++i) {
        int idx = base + i;
        if (idx < NN) s += counts[idx];
    }
    sm[t] = s;
    __syncthreads();
    for (int off = 1; off < 1024; off <<= 1) {
        int v = (t >= off) ? sm[t - off] : 0;
        __syncthreads();
        sm[t] += v;
        __syncthreads();
    }
    int run = sm[t] - s;
    for (int i = 0; i < per; ++i) {
        int idx = base + i;
        if (idx < NN) {
            row_start[idx] = run;
            cursor[idx] = run;
            run += counts[idx];
        }
    }
    if (t == 1023) row_start[NN] = sm[1023];
}

__global__ void scatter_kernel(const int* __restrict__ src, const int* __restrict__ dst,
                               const float* __restrict__ weight, int* cursor,
                               int* src_sorted, float* w_sorted) {
    for (int i = blockIdx.x * blockDim.x + threadIdx.x; i < EE; i += gridDim.x * blockDim.x) {
        int pos = atomicAdd(&cursor[dst[i]], 1);
        src_sorted[pos] = src[i];
        w_sorted[pos] = weight[i];
    }
}

// ---------------- MFMA GEMM -> yb (bf16), fused el/er epilogue ----------------
__global__ __launch_bounds__(256) void gemm_mfma(const unsigned short* __restrict__ xb,
                                                 const unsigned short* __restrict__ wb,
                                                 const float* __restrict__ gate_m_b,
                                                 const float* __restrict__ attn_l,
                                                 const float* __restrict__ attn_r,
                                                 unsigned short* __restrict__ yb,
                                                 float* __restrict__ el,
                                                 float* __restrict__ er) {
    __shared__ unsigned short lx[128 * 136];
    __shared__ unsigned short lw[128 * 136];
    int tid = threadIdx.x;
    int row0 = blockIdx.x * 128;
    int jc = blockIdx.y;   // 0,1: feat halves (heads 2jc,2jc+1); 2: mz

    #pragma unroll
    for (int c = 0; c < 8; ++c) {
        int chunk = c * 256 + tid;
        int r = chunk >> 4, seg = chunk & 15;
        int gr = row0 + r; if (gr >= NN) gr = NN - 1;
        *(s8v*)&lx[r * 136 + seg * 8] = *(const s8v*)&xb[(size_t)gr * 128 + seg * 8];
        *(s8v*)&lw[r * 136 + seg * 8] = *(const s8v*)&wb[(size_t)(jc * 128 + r) * 128 + seg * 8];
    }
    __syncthreads();

    int lane = tid & 63, w = tid >> 6;
    int wr = w >> 1, wc = w & 1;
    int lrow = lane & 15, lhi = lane >> 4;
    f4v acc[4][4] = {};
    const unsigned short* pax = &lx[(wr * 64 + lrow) * 136 + lhi * 8];
    const unsigned short* pbw = &lw[(wc * 64 + lrow) * 136 + lhi * 8];
    #pragma unroll
    for (int kk = 0; kk < 4; ++kk) {
        s8v a[4], b[4];
        #pragma unroll
        for (int mi = 0; mi < 4; ++mi) a[mi] = *(const s8v*)(pax + mi * 16 * 136 + kk * 32);
        #pragma unroll
        for (int ni = 0; ni < 4; ++ni) b[ni] = *(const s8v*)(pbw + ni * 16 * 136 + kk * 32);
        #pragma unroll
        for (int mi = 0; mi < 4; ++mi)
            #pragma unroll
            for (int ni = 0; ni < 4; ++ni)
                acc[mi][ni] = __builtin_amdgcn_mfma_f32_16x16x32_bf16(a[mi], b[ni], acc[mi][ni], 0, 0, 0);
    }

    #pragma unroll
    for (int ni = 0; ni < 4; ++ni) {
        int gcol = jc * 128 + wc * 64 + ni * 16 + lrow;
        float bias = (gcol >= 256) ? gate_m_b[gcol - 256] : 0.0f;
        #pragma unroll
        for (int mi = 0; mi < 4; ++mi) {
            int grow0 = row0 + wr * 64 + mi * 16 + lhi * 4;
            #pragma unroll
            for (int rg = 0; rg < 4; ++rg) {
                int grow = grow0 + rg;
                if (grow < NN) yb[(size_t)grow * JTOT + gcol] = f2bf(acc[mi][ni][rg] + bias);
            }
        }
    }

    if (jc < 2) {
        int head = jc * 2 + wc;
        #pragma unroll
        for (int mi = 0; mi < 4; ++mi) {
            float tl[4] = {0, 0, 0, 0}, tr[4] = {0, 0, 0, 0};
            #pragma unroll
            for (int ni = 0; ni < 4; ++ni) {
                float al = attn_l[head * 64 + ni * 16 + lrow];
                float ar = attn_r[head * 64 + ni * 16 + lrow];
                #pragma unroll
                for (int rg = 0; rg < 4; ++rg) {
                    tl[rg] += acc[mi][ni][rg] * al;
                    tr[rg] += acc[mi][ni][rg] * ar;
                }
            }
            #pragma unroll
            for (int off = 1; off < 16; off <<= 1) {
                #pragma unroll
                for (int rg = 0; rg < 4; ++rg) {
                    tl[rg] += __shfl_xor(tl[rg], off, 64);
                    tr[rg] += __shfl_xor(tr[rg], off, 64);
                }
            }
            if (lrow == 0) {
                int grow0 = row0 + wr * 64 + mi * 16 + lhi * 4;
                #pragma unroll
                for (int rg = 0; rg < 4; ++rg) {
                    int grow = grow0 + rg;
                    if (grow < NN) {
                        el[grow * 4 + head] = tl[rg];
                        er[grow * 4 + head] = tr[rg];
                    }
                }
            }
        }
    }
}

// ---------------- single-pass per-node aggregation + gate -> gated (bf16 [N,64]) ----------------
// lane owns head h=lane>>4, cols 4*(lane&15)..+3 of that head.
__global__ __launch_bounds__(256, 8) void node_kernel(const unsigned short* __restrict__ yb,
                                                      const unsigned short* __restrict__ xb,
                                                      const float* __restrict__ el,
                                                      const float* __restrict__ er,
                                                      const int* __restrict__ row_start,
                                                      const int* __restrict__ src_sorted,
                                                      const float* __restrict__ w_sorted,
                                                      const float* __restrict__ gate_fn_w,
                                                      const float* __restrict__ gate_fn_b,
                                                      unsigned short* __restrict__ gb) {
    int lane = threadIdx.x & 63, wv = threadIdx.x >> 6;
    int n = blockIdx.x * 4 + wv;
    if (n >= NN) return;
    int rs = row_start[n], re = row_start[n + 1];
    bool s1 = (lane & 16) != 0, s2 = (lane & 32) != 0;

    float4 er4 = ((const float4*)er)[n];
    float e01 = s1 ? er4.y : er4.x;
    float e23 = s1 ? er4.w : er4.z;
    float ern = s2 ? e23 : e01;

    float mz0 = -INFINITY, mz1 = -INFINITY;
    float sx0 = 0.f, sx1 = 0.f, se = 0.f;
    float ac0 = 0.f, ac1 = 0.f, ac2 = 0.f, ac3 = 0.f;

    for (int idx = rs; idx < re; ++idx) {
        int s = src_sorted[idx];
        float wgt = w_sorted[idx];
        float4 el4 = ((const float4*)el)[s];
        const unsigned short* yr = yb + (size_t)s * JTOT;
        ushort4 f4 = *(const ushort4*)(yr + 4 * lane);
        ushort2 m2 = *(const ushort2*)(yr + 256 + 2 * lane);
        ushort2 xg = *(const ushort2*)(xb + (size_t)s * 128 + 2 * lane);

        float l01 = s1 ? el4.y : el4.x;
        float l23 = s1 ? el4.w : el4.z;
        float t = (s2 ? l23 : l01) + ern;
        t = (t > 0.f) ? t : 0.2f * t;
        float ex = __expf(t);
        se += ex;
        float axw = ex * wgt;
        ac0 += axw * bf2f(f4.x);
        ac1 += axw * bf2f(f4.y);
        ac2 += axw * bf2f(f4.z);
        ac3 += axw * bf2f(f4.w);
        mz0 = fmaxf(mz0, bf2f(m2.x));
        mz1 = fmaxf(mz1, bf2f(m2.y));
        sx0 += bf2f(xg.x);
        sx1 += bf2f(xg.y);
    }
    if (re == rs) { mz0 = mz1 = 0.f; }
    float deg = (float)(re - rs);
    float invd = 1.0f / fmaxf(deg, 1.0f);
    float mn0 = sx0 * invd, mn1 = sx1 * invd;

    ushort2 xs = *(const ushort2*)(xb + (size_t)n * 128 + 2 * lane);
    float x2x = bf2f(xs.x), x2y = bf2f(xs.y);

    float gate[4];
    #pragma unroll
    for (int h = 0; h < 4; ++h) {
        const float* gw = gate_fn_w + h * 384;
        float2 g0 = *(const float2*)(gw + 2 * lane);
        float2 g1 = *(const float2*)(gw + 128 + 2 * lane);
        float2 g2 = *(const float2*)(gw + 256 + 2 * lane);
        float p = g0.x * x2x + g0.y * x2y + g1.x * mz0 + g1.y * mz1
                + g2.x * mn0 + g2.y * mn1;
        #pragma unroll
        for (int o = 1; o < 64; o <<= 1) p += __shfl_xor(p, o, 64);
        gate[h] = 1.0f / (1.0f + __expf(-(p + gate_fn_b[h])));
    }
    float g01 = s1 ? gate[1] : gate[0];
    float g23 = s1 ? gate[3] : gate[2];
    float gown = s2 ? g23 : g01;
    float scale = gown / fmaxf(se, 1e-30f);

    float p0 = ac0 * scale, p1 = ac1 * scale, p2 = ac2 * scale, p3 = ac3 * scale;
    p0 += __shfl_xor(p0, 16, 64); p1 += __shfl_xor(p1, 16, 64);
    p2 += __shfl_xor(p2, 16, 64); p3 += __shfl_xor(p3, 16, 64);
    p0 += __shfl_xor(p0, 32, 64); p1 += __shfl_xor(p1, 32, 64);
    p2 += __shfl_xor(p2, 32, 64); p3 += __shfl_xor(p3, 32, 64);
    p0 *= 0.25f; p1 *= 0.25f; p2 *= 0.25f; p3 *= 0.25f;

    if (lane < 16) {
        ushort4 o;
        o.x = f2bf(p0); o.y = f2bf(p1); o.z = f2bf(p2); o.w = f2bf(p3);
        *(ushort4*)&gb[(size_t)n * 64 + lane * 4] = o;
    }
}

// ---------------- merger GEMM: out[N,64] = [xb|gb][N,192] @ wmb[64,192]^T + b ----------------
__global__ __launch_bounds__(256) void merge_mfma(const unsigned short* __restrict__ xb,
                                                  const unsigned short* __restrict__ gb,
                                                  const unsigned short* __restrict__ wmb,
                                                  const float* __restrict__ merger_b,
                                                  float* __restrict__ out) {
    __shared__ unsigned short la[128 * 200];   // 192 cols + pad 8 halves
    int tid = threadIdx.x;
    int row0 = blockIdx.x * 128;
    for (int c = tid; c < 128 * 24; c += 256) {
        int r = c / 24, seg = c % 24;
        int gr = row0 + r; if (gr >= NN) gr = NN - 1;
        s8v v = (seg < 16) ? *(const s8v*)&xb[(size_t)gr * 128 + seg * 8]
                           : *(const s8v*)&gb[(size_t)gr * 64 + (seg - 16) * 8];
        *(s8v*)&la[r * 200 + seg * 8] = v;
    }
    __syncthreads();

    int lane = tid & 63, w = tid >> 6;   // wave w: rows w*32..+31
    int lrow = lane & 15, lhi = lane >> 4;
    f4v acc[2][4] = {};
    const unsigned short* pa = &la[(w * 32 + lrow) * 200 + lhi * 8];
    #pragma unroll
    for (int kk = 0; kk < 6; ++kk) {
        s8v a0 = *(const s8v*)(pa + kk * 32);
        s8v a1 = *(const s8v*)(pa + 16 * 200 + kk * 32);
        #pragma unroll
        for (int ni = 0; ni < 4; ++ni) {
            s8v b = *(const s8v*)&wmb[(size_t)(ni * 16 + lrow) * 192 + kk * 32 + lhi * 8];
            acc[0][ni] = __builtin_amdgcn_mfma_f32_16x16x32_bf16(a0, b, acc[0][ni], 0, 0, 0);
            acc[1][ni] = __builtin_amdgcn_mfma_f32_16x16x32_bf16(a1, b, acc[1][ni], 0, 0, 0);
        }
    }
    #pragma unroll
    for (int ni = 0; ni < 4; ++ni) {
        int gcol = ni * 16 + lrow;
        float bias = merger_b[gcol];
        #pragma unroll
        for (int mi = 0; mi < 2; ++mi) {
            #pragma unroll
            for (int rg = 0; rg < 4; ++rg) {
                int grow = row0 + w * 32 + mi * 16 + lhi * 4 + rg;
                if (grow < NN) out[(size_t)grow * 64 + gcol] = acc[mi][ni][rg] + bias;
            }
        }
    }
}

extern "C" void kernel_launch(void* const* d_in, const int* in_sizes, int n_in,
                              void* d_out, int out_size, void* d_ws, size_t ws_size,
                              hipStream_t stream) {
    const float* x         = (const float*)d_in[0];
    const int*   src       = (const int*)d_in[1];
    const int*   dst       = (const int*)d_in[2];
    const float* weight    = (const float*)d_in[3];
    const float* fc_w      = (const float*)d_in[4];
    const float* attn_l    = (const float*)d_in[5];
    const float* attn_r    = (const float*)d_in[6];
    const float* gate_m_w  = (const float*)d_in[7];
    const float* gate_m_b  = (const float*)d_in[8];
    const float* gate_fn_w = (const float*)d_in[9];
    const float* gate_fn_b = (const float*)d_in[10];
    const float* merger_w  = (const float*)d_in[11];
    const float* merger_b  = (const float*)d_in[12];
    float* out = (float*)d_out;

    char* p = (char*)d_ws;
    auto alloc = [&](size_t bytes) {
        char* r = p;
        p += (bytes + 255) & ~(size_t)255;
        return r;
    };
    unsigned short* yb  = (unsigned short*)alloc((size_t)NN * JTOT * 2);
    float* el           = (float*)alloc((size_t)NN * 4 * 4);
    float* er           = (float*)alloc((size_t)NN * 4 * 4);
    int*   counts       = (int*)alloc((size_t)NN * 4);
    int*   row_start    = (int*)alloc((size_t)(NN + 1) * 4);
    int*   cursor       = (int*)alloc((size_t)NN * 4);
    int*   src_sorted   = (int*)alloc((size_t)EE * 4);
    float* w_sorted     = (float*)alloc((size_t)EE * 4);
    unsigned short* xb  = (unsigned short*)alloc((size_t)NN * 128 * 2);
    unsigned short* wb  = (unsigned short*)alloc((size_t)384 * 128 * 2);
    unsigned short* wmb = (unsigned short*)alloc((size_t)64 * 192 * 2);
    unsigned short* gbuf= (unsigned short*)alloc((size_t)NN * 64 * 2);

    cvt_kernel<<<1024, 256, 0, stream>>>(x, fc_w, gate_m_w, merger_w, xb, wb, wmb, counts);
    count_kernel<<<1024, 256, 0, stream>>>(dst, counts);
    scan_kernel<<<1, 1024, 0, stream>>>(counts, row_start, cursor);
    scatter_kernel<<<1024, 256, 0, stream>>>(src, dst, weight, cursor, src_sorted, w_sorted);
    gemm_mfma<<<dim3((NN + 127) / 128, 3), 256, 0, stream>>>(xb, wb, gate_m_b, attn_l, attn_r,
                                                             yb, el, er);
    node_kernel<<<NN / 4, 256, 0, stream>>>(yb, xb, el, er, row_start, src_sorted, w_sorted,
                                            gate_fn_w, gate_fn_b, gbuf);
    merge_mfma<<<(NN + 127) / 128, 256, 0, stream>>>(xb, gbuf, wmb, merger_b, out);
}